// Round 7
// baseline (380.636 us; speedup 1.0000x reference)
//
#include <hip/hip_runtime.h>

#define FIN 100
#define FHID 100
#define FEMB 64
#define NCLS 40

#define BSH 6                 // 64 nodes per bucket
#define NSEG 8                // segments per bucket (reduces atomic contention)
#define SEGCAP 224            // >= E/NBK/NSEG (=128) + 8.5 sigma; overflow prob ~1e-15

// ---------- bf16 helpers (OCP bf16 = fp32 high half, RNE) ----------
__device__ inline unsigned short f2bf(float f) {
    unsigned u = __float_as_uint(f);
    u += 0x7FFFu + ((u >> 16) & 1u);
    return (unsigned short)(u >> 16);
}
__device__ inline float bf2f(unsigned short s) {
    return __uint_as_float((unsigned)s << 16);
}
__device__ inline float4 bf4(ushort4 u) {
    return make_float4(bf2f(u.x), bf2f(u.y), bf2f(u.z), bf2f(u.w));
}

// ============ phase B: scatter edges into per-(bucket,segment) arenas ============
__global__ void k_bucket_scatter(const int* __restrict__ src, const int* __restrict__ dst,
                                 int* __restrict__ cur, int* __restrict__ arena, int E) {
    int e = blockIdx.x * blockDim.x + threadIdx.x;
    if (e >= E) return;
    int d = dst[e];
    int b = d >> BSH;
    int slot = b * NSEG + (blockIdx.x & (NSEG - 1));
    int p = atomicAdd(&cur[slot], 1);
    if (p < SEGCAP) arena[slot * SEGCAP + p] = (src[e] << BSH) | (d & 63);
}

// ============ scan bucket totals -> bucket base offsets (single block; nbk <= 1024) ============
__global__ __launch_bounds__(1024) void k_bucket_scan(const int* __restrict__ cur,
                                                      int* __restrict__ bbase,
                                                      int* __restrict__ rowptr,
                                                      int nbk, int n, int E) {
    __shared__ int t[1024];
    int b = threadIdx.x;
    int v = 0;
    if (b < nbk) {
        #pragma unroll
        for (int s = 0; s < NSEG; ++s) v += cur[b * NSEG + s];
    }
    t[b] = v;
    __syncthreads();
    for (int off = 1; off < 1024; off <<= 1) {
        int add = (b >= off) ? t[b - off] : 0;
        __syncthreads();
        t[b] += add;
        __syncthreads();
    }
    if (b < nbk) bbase[b] = t[b] - v;  // exclusive
    if (b == 0) rowptr[n] = E;
}

// ============ phase C: per-bucket counting sort -> rowptr, dinv, compact src_sorted ============
__global__ __launch_bounds__(256) void k_bucket_sort(const int* __restrict__ arena,
                                                     const int* __restrict__ cur,
                                                     const int* __restrict__ bbase,
                                                     int* __restrict__ rowptr,
                                                     float* __restrict__ dinv,
                                                     int* __restrict__ src_sorted, int n) {
    const int b = blockIdx.x;
    const int base = bbase[b];
    __shared__ int cnt[64], off[64];
    if (threadIdx.x < 64) cnt[threadIdx.x] = 0;
    __syncthreads();
    for (int s = 0; s < NSEG; ++s) {
        const int len = cur[b * NSEG + s];
        const int* seg = arena + (size_t)(b * NSEG + s) * SEGCAP;
        for (int idx = threadIdx.x; idx < len; idx += 256)
            atomicAdd(&cnt[seg[idx] & 63], 1);
    }
    __syncthreads();
    if (threadIdx.x == 0) {
        int run = 0;
        for (int j = 0; j < 64; ++j) { off[j] = run; run += cnt[j]; }
    }
    __syncthreads();
    if (threadIdx.x < 64) {
        int node = (b << BSH) + threadIdx.x;
        if (node < n) {
            rowptr[node] = base + off[threadIdx.x];
            dinv[node] = rsqrtf((float)cnt[threadIdx.x] + 1.0f);  // +1 self-loop
        }
    }
    __syncthreads();
    for (int s = 0; s < NSEG; ++s) {
        const int len = cur[b * NSEG + s];
        const int* seg = arena + (size_t)(b * NSEG + s) * SEGCAP;
        for (int idx = threadIdx.x; idx < len; idx += 256) {
            int v = seg[idx];
            int lpos = atomicAdd(&off[v & 63], 1);
            src_sorted[base + lpos] = v >> BSH;
        }
    }
}

// ====== GEMM: thread-per-row, A-row in VGPRs, W col-slice in LDS (broadcast reads) ======
// grid = (ceil(n/256), NSPLIT). OUT_BF16: C stored as bf16 [n][KOUT].
template <int KIN, int KOUT, int NSPLIT, bool RELU_IN, bool BIAS, bool OUT_BF16>
__global__ __launch_bounds__(256) void k_gemm_reg(const float* __restrict__ A,
                                                  const float* __restrict__ W,
                                                  const float* __restrict__ bias,
                                                  void* __restrict__ C, int n) {
    constexpr int NG = KOUT / 4;
    constexpr int GMAX = (NG + NSPLIT - 1) / NSPLIT;
    __shared__ float Ws[KIN * GMAX * 4];

    const int g0 = blockIdx.y * GMAX;
    const int gw = (g0 + GMAX <= NG) ? GMAX : (NG - g0);
    const int wcols = gw * 4;

    for (int idx = threadIdx.x; idx < KIN * wcols; idx += 256) {
        int k = idx / wcols;
        int cc = idx - k * wcols;
        Ws[k * (GMAX * 4) + cc] = W[k * KOUT + g0 * 4 + cc];
    }

    const int row = blockIdx.x * 256 + threadIdx.x;
    const bool active = row < n;
    float4 a[KIN / 4];
    if (active) {
        const float4* arow = (const float4*)(A + (size_t)row * KIN);
        #pragma unroll
        for (int i = 0; i < KIN / 4; ++i) {
            float4 v = arow[i];
            if (RELU_IN) {
                v.x = fmaxf(v.x, 0.f); v.y = fmaxf(v.y, 0.f);
                v.z = fmaxf(v.z, 0.f); v.w = fmaxf(v.w, 0.f);
            }
            a[i] = v;
        }
    }
    __syncthreads();
    if (!active) return;

    for (int g = 0; g < gw; ++g) {
        float4 acc;
        if (BIAS) acc = *(const float4*)&bias[(g0 + g) * 4];
        else      acc = make_float4(0.f, 0.f, 0.f, 0.f);
        const float* wbase = &Ws[g * 4];
        #pragma unroll
        for (int kq = 0; kq < KIN / 4; ++kq) {
            const float4 av = a[kq];
            const float4 w0 = *(const float4*)&wbase[(kq * 4 + 0) * (GMAX * 4)];
            const float4 w1 = *(const float4*)&wbase[(kq * 4 + 1) * (GMAX * 4)];
            const float4 w2 = *(const float4*)&wbase[(kq * 4 + 2) * (GMAX * 4)];
            const float4 w3 = *(const float4*)&wbase[(kq * 4 + 3) * (GMAX * 4)];
            acc.x = fmaf(av.x, w0.x, acc.x); acc.y = fmaf(av.x, w0.y, acc.y);
            acc.z = fmaf(av.x, w0.z, acc.z); acc.w = fmaf(av.x, w0.w, acc.w);
            acc.x = fmaf(av.y, w1.x, acc.x); acc.y = fmaf(av.y, w1.y, acc.y);
            acc.z = fmaf(av.y, w1.z, acc.z); acc.w = fmaf(av.y, w1.w, acc.w);
            acc.x = fmaf(av.z, w2.x, acc.x); acc.y = fmaf(av.z, w2.y, acc.y);
            acc.z = fmaf(av.z, w2.z, acc.z); acc.w = fmaf(av.z, w2.w, acc.w);
            acc.x = fmaf(av.w, w3.x, acc.x); acc.y = fmaf(av.w, w3.y, acc.y);
            acc.z = fmaf(av.w, w3.z, acc.z); acc.w = fmaf(av.w, w3.w, acc.w);
        }
        if (OUT_BF16) {
            ushort4 o;
            o.x = f2bf(acc.x); o.y = f2bf(acc.y); o.z = f2bf(acc.z); o.w = f2bf(acc.w);
            *(ushort4*)((unsigned short*)C + (size_t)row * KOUT + (g0 + g) * 4) = o;
        } else {
            *(float4*)((float*)C + (size_t)row * KOUT + (g0 + g) * 4) = acc;
        }
    }
}

// ===== row-major CSR aggregation over bf16 h: out_i = b + d_i*(d_i*h_i + sum dinv[s]*h[s]) =====
template <int F>
__global__ __launch_bounds__(256) void k_agg_bf(const unsigned short* __restrict__ h,
                                                const int* __restrict__ rowptr,
                                                const int* __restrict__ src_sorted,
                                                const float* __restrict__ dinv,
                                                const float* __restrict__ bias,
                                                float* __restrict__ out, int n) {
    const int G = F / 4;
    int gid = blockIdx.x * blockDim.x + threadIdx.x;
    if (gid >= n * G) return;
    int i = gid / G;
    int cq = gid % G;
    const ushort4* h4 = (const ushort4*)h;

    float4 acc = make_float4(0.f, 0.f, 0.f, 0.f);
    int e = rowptr[i];
    const int end = rowptr[i + 1];
    for (; e + 3 < end; e += 4) {
        int s0 = src_sorted[e];
        int s1 = src_sorted[e + 1];
        int s2 = src_sorted[e + 2];
        int s3 = src_sorted[e + 3];
        ushort4 u0 = h4[(size_t)s0 * G + cq];
        ushort4 u1 = h4[(size_t)s1 * G + cq];
        ushort4 u2 = h4[(size_t)s2 * G + cq];
        ushort4 u3 = h4[(size_t)s3 * G + cq];
        float n0 = dinv[s0];
        float n1 = dinv[s1];
        float n2 = dinv[s2];
        float n3 = dinv[s3];
        float4 v0 = bf4(u0), v1 = bf4(u1), v2 = bf4(u2), v3 = bf4(u3);
        acc.x = fmaf(v0.x, n0, acc.x); acc.y = fmaf(v0.y, n0, acc.y);
        acc.z = fmaf(v0.z, n0, acc.z); acc.w = fmaf(v0.w, n0, acc.w);
        acc.x = fmaf(v1.x, n1, acc.x); acc.y = fmaf(v1.y, n1, acc.y);
        acc.z = fmaf(v1.z, n1, acc.z); acc.w = fmaf(v1.w, n1, acc.w);
        acc.x = fmaf(v2.x, n2, acc.x); acc.y = fmaf(v2.y, n2, acc.y);
        acc.z = fmaf(v2.z, n2, acc.z); acc.w = fmaf(v2.w, n2, acc.w);
        acc.x = fmaf(v3.x, n3, acc.x); acc.y = fmaf(v3.y, n3, acc.y);
        acc.z = fmaf(v3.z, n3, acc.z); acc.w = fmaf(v3.w, n3, acc.w);
    }
    for (; e < end; ++e) {
        int s0 = src_sorted[e];
        float n0 = dinv[s0];
        float4 v0 = bf4(h4[(size_t)s0 * G + cq]);
        acc.x = fmaf(v0.x, n0, acc.x); acc.y = fmaf(v0.y, n0, acc.y);
        acc.z = fmaf(v0.z, n0, acc.z); acc.w = fmaf(v0.w, n0, acc.w);
    }

    float d = dinv[i];
    float4 hv = bf4(h4[(size_t)i * G + cq]);
    float4 bv = *(const float4*)&bias[cq * 4];
    float4 o;
    o.x = fmaf(d, fmaf(d, hv.x, acc.x), bv.x);
    o.y = fmaf(d, fmaf(d, hv.y, acc.y), bv.y);
    o.z = fmaf(d, fmaf(d, hv.z, acc.z), bv.z);
    o.w = fmaf(d, fmaf(d, hv.w, acc.w), bv.w);
    ((float4*)out)[(size_t)i * G + cq] = o;
}

extern "C" void kernel_launch(void* const* d_in, const int* in_sizes, int n_in,
                              void* d_out, int out_size, void* d_ws, size_t ws_size,
                              hipStream_t stream) {
    const float* x  = (const float*)d_in[0];
    const int*   ei = (const int*)d_in[1];
    const float* W1 = (const float*)d_in[2];
    const float* b1 = (const float*)d_in[3];
    const float* W2 = (const float*)d_in[4];
    const float* b2 = (const float*)d_in[5];
    const float* Wc = (const float*)d_in[6];
    const float* bc = (const float*)d_in[7];
    float* out = (float*)d_out;

    const int N = in_sizes[0] / FIN;
    const int E = in_sizes[1] / 2;
    const int* src = ei;
    const int* dst = ei + E;
    const int NBK = (N + 63) >> BSH;  // 782 for N=50k; k_bucket_scan requires <= 1024

    auto align = [](size_t v) { return (v + 255) & ~(size_t)255; };
    char* ws = (char*)d_ws;
    int*   cur        = (int*)ws;   ws += align((size_t)NBK * NSEG * 4);
    int*   bbase      = (int*)ws;   ws += align((size_t)(NBK + 1) * 4);
    int*   arena      = (int*)ws;   ws += align((size_t)NBK * NSEG * SEGCAP * 4);
    int*   rowptr     = (int*)ws;   ws += align((size_t)(N + 1) * 4);
    int*   src_sorted = (int*)ws;   ws += align((size_t)E * 4);
    float* dinv       = (float*)ws; ws += align((size_t)N * 4);
    unsigned short* hbf = (unsigned short*)ws; ws += align((size_t)N * FHID * 2);  // bf16 h1/h2
    float* abuf       = (float*)ws; ws += align((size_t)N * FHID * 4);             // fp32 a1/a2

    const int B = 256;
    const int nb = (N + 255) / 256;

    // --- bucketed counting sort (CSR shared by both conv layers) ---
    hipMemsetAsync(cur, 0, (size_t)NBK * NSEG * 4, stream);
    k_bucket_scatter<<<(E + B - 1) / B, B, 0, stream>>>(src, dst, cur, arena, E);
    k_bucket_scan<<<1, 1024, 0, stream>>>(cur, bbase, rowptr, NBK, N, E);
    k_bucket_sort<<<NBK, B, 0, stream>>>(arena, cur, bbase, rowptr, dinv, src_sorted, N);

    // --- layer 1: h1(bf16) = x @ W1 ; a1 = agg(h1) + b1 ---
    k_gemm_reg<FIN, FHID, 4, false, false, true><<<dim3(nb, 4), B, 0, stream>>>(x, W1, nullptr, hbf, N);
    k_agg_bf<FHID><<<((size_t)N * (FHID / 4) + B - 1) / B, B, 0, stream>>>(
        hbf, rowptr, src_sorted, dinv, b1, abuf, N);

    // --- layer 2: h2(bf16) = relu(a1) @ W2 ; a2 = agg(h2) + b2 ---
    k_gemm_reg<FHID, FEMB, 4, true, false, true><<<dim3(nb, 4), B, 0, stream>>>(abuf, W2, nullptr, hbf, N);
    k_agg_bf<FEMB><<<((size_t)N * (FEMB / 4) + B - 1) / B, B, 0, stream>>>(
        hbf, rowptr, src_sorted, dinv, b2, abuf, N);

    // --- classifier: out = relu(a2) @ Wc + bc ---
    k_gemm_reg<FEMB, NCLS, 4, true, true, false><<<dim3(nb, 4), B, 0, stream>>>(abuf, Wc, bc, out, N);
}

// Round 8
// 269.954 us; speedup vs baseline: 1.4100x; 1.4100x over previous
//
#include <hip/hip_runtime.h>

#define FIN 100
#define FHID 100
#define FEMB 64
#define NCLS 40

#define BSH 6                 // 64 nodes per bucket
#define NSEG 8                // segments per bucket (reduces atomic contention)
#define SEGCAP 224            // >= E/NBK/NSEG (=128) + 8.5 sigma; overflow prob ~1e-15

// ---------- bf16 helpers (OCP bf16 = fp32 high half, RNE) ----------
__device__ inline unsigned short f2bf(float f) {
    unsigned u = __float_as_uint(f);
    u += 0x7FFFu + ((u >> 16) & 1u);
    return (unsigned short)(u >> 16);
}
__device__ inline float bf2f(unsigned short s) {
    return __uint_as_float((unsigned)s << 16);
}
__device__ inline float4 bf4(ushort4 u) {
    return make_float4(bf2f(u.x), bf2f(u.y), bf2f(u.z), bf2f(u.w));
}

// ============ phase B: scatter edges into per-(bucket,segment) arenas ============
__global__ void k_bucket_scatter(const int* __restrict__ src, const int* __restrict__ dst,
                                 int* __restrict__ cur, int* __restrict__ arena, int E) {
    int e = blockIdx.x * blockDim.x + threadIdx.x;
    if (e >= E) return;
    int d = dst[e];
    int b = d >> BSH;
    int slot = b * NSEG + (blockIdx.x & (NSEG - 1));
    int p = atomicAdd(&cur[slot], 1);
    if (p < SEGCAP) arena[slot * SEGCAP + p] = (src[e] << BSH) | (d & 63);
}

// ============ scan bucket totals -> bucket base offsets (single block; nbk <= 1024) ============
__global__ __launch_bounds__(1024) void k_bucket_scan(const int* __restrict__ cur,
                                                      int* __restrict__ bbase,
                                                      int* __restrict__ rowptr,
                                                      int nbk, int n, int E) {
    __shared__ int t[1024];
    int b = threadIdx.x;
    int v = 0;
    if (b < nbk) {
        #pragma unroll
        for (int s = 0; s < NSEG; ++s) v += cur[b * NSEG + s];
    }
    t[b] = v;
    __syncthreads();
    for (int off = 1; off < 1024; off <<= 1) {
        int add = (b >= off) ? t[b - off] : 0;
        __syncthreads();
        t[b] += add;
        __syncthreads();
    }
    if (b < nbk) bbase[b] = t[b] - v;  // exclusive
    if (b == 0) rowptr[n] = E;
}

// ============ phase C: per-bucket counting sort -> rowptr, dinv, compact src_sorted ============
__global__ __launch_bounds__(256) void k_bucket_sort(const int* __restrict__ arena,
                                                     const int* __restrict__ cur,
                                                     const int* __restrict__ bbase,
                                                     int* __restrict__ rowptr,
                                                     float* __restrict__ dinv,
                                                     int* __restrict__ src_sorted, int n) {
    const int b = blockIdx.x;
    const int base = bbase[b];
    __shared__ int cnt[64], off[64];
    if (threadIdx.x < 64) cnt[threadIdx.x] = 0;
    __syncthreads();
    for (int s = 0; s < NSEG; ++s) {
        const int len = cur[b * NSEG + s];
        const int* seg = arena + (size_t)(b * NSEG + s) * SEGCAP;
        for (int idx = threadIdx.x; idx < len; idx += 256)
            atomicAdd(&cnt[seg[idx] & 63], 1);
    }
    __syncthreads();
    if (threadIdx.x == 0) {
        int run = 0;
        for (int j = 0; j < 64; ++j) { off[j] = run; run += cnt[j]; }
    }
    __syncthreads();
    if (threadIdx.x < 64) {
        int node = (b << BSH) + threadIdx.x;
        if (node < n) {
            rowptr[node] = base + off[threadIdx.x];
            dinv[node] = rsqrtf((float)cnt[threadIdx.x] + 1.0f);  // +1 self-loop
        }
    }
    __syncthreads();
    for (int s = 0; s < NSEG; ++s) {
        const int len = cur[b * NSEG + s];
        const int* seg = arena + (size_t)(b * NSEG + s) * SEGCAP;
        for (int idx = threadIdx.x; idx < len; idx += 256) {
            int v = seg[idx];
            int lpos = atomicAdd(&off[v & 63], 1);
            src_sorted[base + lpos] = v >> BSH;
        }
    }
}

// ====== tiled GEMM: 64x64 block tile, 4x4 microtile/thread, A transposed in LDS ======
// grid = (ceil(n/64), ceil(KOUT/64)). KOUT % 4 == 0 assumed.
template <int KIN, int KOUT, bool RELU_IN, bool BIAS, bool OUT_BF16>
__global__ __launch_bounds__(256) void k_gemm_tile(const float* __restrict__ A,
                                                   const float* __restrict__ W,
                                                   const float* __restrict__ bias,
                                                   void* __restrict__ C, int n) {
    constexpr int KQ = KIN / 4;
    constexpr int AST = 66;  // As leading stride (floats): even (8B-aligned b64) but not mult-of-8 (bank spread)
    __shared__ float As[KIN * AST];   // [k][r]
    __shared__ float Ws[KIN * 64];    // [k][c]

    const int row0 = blockIdx.x * 64;
    const int col0 = blockIdx.y * 64;

    // stage A[row0:row0+64, :] transposed -> As[k][r] (coalesced float4 global reads)
    for (int idx = threadIdx.x; idx < 64 * KQ; idx += 256) {
        int r = idx / KQ;
        int kq = idx - r * KQ;
        float4 v = make_float4(0.f, 0.f, 0.f, 0.f);
        if (row0 + r < n) {
            v = ((const float4*)(A + (size_t)(row0 + r) * KIN))[kq];
            if (RELU_IN) {
                v.x = fmaxf(v.x, 0.f); v.y = fmaxf(v.y, 0.f);
                v.z = fmaxf(v.z, 0.f); v.w = fmaxf(v.w, 0.f);
            }
        }
        As[(4 * kq + 0) * AST + r] = v.x;
        As[(4 * kq + 1) * AST + r] = v.y;
        As[(4 * kq + 2) * AST + r] = v.z;
        As[(4 * kq + 3) * AST + r] = v.w;
    }
    // stage W[:, col0:col0+64] -> Ws[k][c], zero-padded past KOUT
    for (int idx = threadIdx.x; idx < KIN * 64; idx += 256) {
        int k = idx >> 6;
        int c = idx & 63;
        Ws[idx] = (col0 + c < KOUT) ? W[(size_t)k * KOUT + col0 + c] : 0.f;
    }
    __syncthreads();

    const int tx = threadIdx.x & 15;   // row quad index
    const int ty = threadIdx.x >> 4;   // col quad index
    const int ra = tx * 4;
    const int ca = ty * 4;
    const bool cok = (col0 + ca < KOUT);  // whole quad in or out (KOUT % 4 == 0)

    float acc[4][4];
    #pragma unroll
    for (int i = 0; i < 4; ++i) {
        #pragma unroll
        for (int j = 0; j < 4; ++j) acc[i][j] = 0.f;
    }
    if (BIAS && cok) {
        float4 bv = *(const float4*)&bias[col0 + ca];
        #pragma unroll
        for (int i = 0; i < 4; ++i) {
            acc[i][0] = bv.x; acc[i][1] = bv.y; acc[i][2] = bv.z; acc[i][3] = bv.w;
        }
    }

    #pragma unroll 4
    for (int k = 0; k < KIN; ++k) {
        float2 a01 = *(const float2*)&As[k * AST + ra];
        float2 a23 = *(const float2*)&As[k * AST + ra + 2];
        float4 w = *(const float4*)&Ws[k * 64 + ca];
        float av0 = a01.x, av1 = a01.y, av2 = a23.x, av3 = a23.y;
        acc[0][0] = fmaf(av0, w.x, acc[0][0]); acc[0][1] = fmaf(av0, w.y, acc[0][1]);
        acc[0][2] = fmaf(av0, w.z, acc[0][2]); acc[0][3] = fmaf(av0, w.w, acc[0][3]);
        acc[1][0] = fmaf(av1, w.x, acc[1][0]); acc[1][1] = fmaf(av1, w.y, acc[1][1]);
        acc[1][2] = fmaf(av1, w.z, acc[1][2]); acc[1][3] = fmaf(av1, w.w, acc[1][3]);
        acc[2][0] = fmaf(av2, w.x, acc[2][0]); acc[2][1] = fmaf(av2, w.y, acc[2][1]);
        acc[2][2] = fmaf(av2, w.z, acc[2][2]); acc[2][3] = fmaf(av2, w.w, acc[2][3]);
        acc[3][0] = fmaf(av3, w.x, acc[3][0]); acc[3][1] = fmaf(av3, w.y, acc[3][1]);
        acc[3][2] = fmaf(av3, w.z, acc[3][2]); acc[3][3] = fmaf(av3, w.w, acc[3][3]);
    }

    if (!cok) return;
    #pragma unroll
    for (int i = 0; i < 4; ++i) {
        int row = row0 + ra + i;
        if (row >= n) break;
        if (OUT_BF16) {
            ushort4 o;
            o.x = f2bf(acc[i][0]); o.y = f2bf(acc[i][1]);
            o.z = f2bf(acc[i][2]); o.w = f2bf(acc[i][3]);
            *(ushort4*)((unsigned short*)C + (size_t)row * KOUT + col0 + ca) = o;
        } else {
            *(float4*)((float*)C + (size_t)row * KOUT + col0 + ca) =
                make_float4(acc[i][0], acc[i][1], acc[i][2], acc[i][3]);
        }
    }
}

// ===== row-major CSR aggregation over bf16 h: out_i = b + d_i*(d_i*h_i + sum dinv[s]*h[s]) =====
template <int F>
__global__ __launch_bounds__(256) void k_agg_bf(const unsigned short* __restrict__ h,
                                                const int* __restrict__ rowptr,
                                                const int* __restrict__ src_sorted,
                                                const float* __restrict__ dinv,
                                                const float* __restrict__ bias,
                                                float* __restrict__ out, int n) {
    const int G = F / 4;
    int gid = blockIdx.x * blockDim.x + threadIdx.x;
    if (gid >= n * G) return;
    int i = gid / G;
    int cq = gid % G;
    const ushort4* h4 = (const ushort4*)h;

    float4 acc = make_float4(0.f, 0.f, 0.f, 0.f);
    int e = rowptr[i];
    const int end = rowptr[i + 1];
    for (; e + 3 < end; e += 4) {
        int s0 = src_sorted[e];
        int s1 = src_sorted[e + 1];
        int s2 = src_sorted[e + 2];
        int s3 = src_sorted[e + 3];
        ushort4 u0 = h4[(size_t)s0 * G + cq];
        ushort4 u1 = h4[(size_t)s1 * G + cq];
        ushort4 u2 = h4[(size_t)s2 * G + cq];
        ushort4 u3 = h4[(size_t)s3 * G + cq];
        float n0 = dinv[s0];
        float n1 = dinv[s1];
        float n2 = dinv[s2];
        float n3 = dinv[s3];
        float4 v0 = bf4(u0), v1 = bf4(u1), v2 = bf4(u2), v3 = bf4(u3);
        acc.x = fmaf(v0.x, n0, acc.x); acc.y = fmaf(v0.y, n0, acc.y);
        acc.z = fmaf(v0.z, n0, acc.z); acc.w = fmaf(v0.w, n0, acc.w);
        acc.x = fmaf(v1.x, n1, acc.x); acc.y = fmaf(v1.y, n1, acc.y);
        acc.z = fmaf(v1.z, n1, acc.z); acc.w = fmaf(v1.w, n1, acc.w);
        acc.x = fmaf(v2.x, n2, acc.x); acc.y = fmaf(v2.y, n2, acc.y);
        acc.z = fmaf(v2.z, n2, acc.z); acc.w = fmaf(v2.w, n2, acc.w);
        acc.x = fmaf(v3.x, n3, acc.x); acc.y = fmaf(v3.y, n3, acc.y);
        acc.z = fmaf(v3.z, n3, acc.z); acc.w = fmaf(v3.w, n3, acc.w);
    }
    for (; e < end; ++e) {
        int s0 = src_sorted[e];
        float n0 = dinv[s0];
        float4 v0 = bf4(h4[(size_t)s0 * G + cq]);
        acc.x = fmaf(v0.x, n0, acc.x); acc.y = fmaf(v0.y, n0, acc.y);
        acc.z = fmaf(v0.z, n0, acc.z); acc.w = fmaf(v0.w, n0, acc.w);
    }

    float d = dinv[i];
    float4 hv = bf4(h4[(size_t)i * G + cq]);
    float4 bv = *(const float4*)&bias[cq * 4];
    float4 o;
    o.x = fmaf(d, fmaf(d, hv.x, acc.x), bv.x);
    o.y = fmaf(d, fmaf(d, hv.y, acc.y), bv.y);
    o.z = fmaf(d, fmaf(d, hv.z, acc.z), bv.z);
    o.w = fmaf(d, fmaf(d, hv.w, acc.w), bv.w);
    ((float4*)out)[(size_t)i * G + cq] = o;
}

extern "C" void kernel_launch(void* const* d_in, const int* in_sizes, int n_in,
                              void* d_out, int out_size, void* d_ws, size_t ws_size,
                              hipStream_t stream) {
    const float* x  = (const float*)d_in[0];
    const int*   ei = (const int*)d_in[1];
    const float* W1 = (const float*)d_in[2];
    const float* b1 = (const float*)d_in[3];
    const float* W2 = (const float*)d_in[4];
    const float* b2 = (const float*)d_in[5];
    const float* Wc = (const float*)d_in[6];
    const float* bc = (const float*)d_in[7];
    float* out = (float*)d_out;

    const int N = in_sizes[0] / FIN;
    const int E = in_sizes[1] / 2;
    const int* src = ei;
    const int* dst = ei + E;
    const int NBK = (N + 63) >> BSH;  // 782 for N=50k; k_bucket_scan requires <= 1024

    auto align = [](size_t v) { return (v + 255) & ~(size_t)255; };
    char* ws = (char*)d_ws;
    int*   cur        = (int*)ws;   ws += align((size_t)NBK * NSEG * 4);
    int*   bbase      = (int*)ws;   ws += align((size_t)(NBK + 1) * 4);
    int*   arena      = (int*)ws;   ws += align((size_t)NBK * NSEG * SEGCAP * 4);
    int*   rowptr     = (int*)ws;   ws += align((size_t)(N + 1) * 4);
    int*   src_sorted = (int*)ws;   ws += align((size_t)E * 4);
    float* dinv       = (float*)ws; ws += align((size_t)N * 4);
    unsigned short* hbf = (unsigned short*)ws; ws += align((size_t)N * FHID * 2);  // bf16 h1/h2
    float* abuf       = (float*)ws; ws += align((size_t)N * FHID * 4);             // fp32 a1/a2

    const int B = 256;
    const int nb = (N + 255) / 256;
    const int ntb = (N + 63) / 64;   // 64-row GEMM tiles

    // --- bucketed counting sort (CSR shared by both conv layers) ---
    hipMemsetAsync(cur, 0, (size_t)NBK * NSEG * 4, stream);
    k_bucket_scatter<<<(E + B - 1) / B, B, 0, stream>>>(src, dst, cur, arena, E);
    k_bucket_scan<<<1, 1024, 0, stream>>>(cur, bbase, rowptr, NBK, N, E);
    k_bucket_sort<<<NBK, B, 0, stream>>>(arena, cur, bbase, rowptr, dinv, src_sorted, N);

    // --- layer 1: h1(bf16) = x @ W1 ; a1 = agg(h1) + b1 ---
    k_gemm_tile<FIN, FHID, false, false, true><<<dim3(ntb, 2), B, 0, stream>>>(x, W1, nullptr, hbf, N);
    k_agg_bf<FHID><<<((size_t)N * (FHID / 4) + B - 1) / B, B, 0, stream>>>(
        hbf, rowptr, src_sorted, dinv, b1, abuf, N);

    // --- layer 2: h2(bf16) = relu(a1) @ W2 ; a2 = agg(h2) + b2 ---
    k_gemm_tile<FHID, FEMB, true, false, true><<<dim3(ntb, 1), B, 0, stream>>>(abuf, W2, nullptr, hbf, N);
    k_agg_bf<FEMB><<<((size_t)N * (FEMB / 4) + B - 1) / B, B, 0, stream>>>(
        hbf, rowptr, src_sorted, dinv, b2, abuf, N);

    // --- classifier: out = relu(a2) @ Wc + bc ---
    k_gemm_tile<FEMB, NCLS, true, true, false><<<dim3(ntb, 1), B, 0, stream>>>(abuf, Wc, bc, out, N);
}

// Round 9
// 239.464 us; speedup vs baseline: 1.5895x; 1.1273x over previous
//
#include <hip/hip_runtime.h>

#define FIN 100
#define FHID 100
#define FEMB 64
#define NCLS 40

#define BSH 6                 // 64 nodes per bucket
#define NSEG 8                // segments per bucket
#define SEGCAP 224            // >= E/NBK/NSEG (=128) + 8.5 sigma
#define CSTR 16               // cursor stride in ints: 1 cursor per 64B line (atomic line-contention fix)

typedef __attribute__((ext_vector_type(8))) short short8;   // 8 bf16 (4 VGPRs) — MFMA A/B frag
typedef __attribute__((ext_vector_type(4))) float f32x4;    // MFMA C/D frag

// ---------- bf16 helpers (RNE) ----------
__device__ inline unsigned short f2bf(float f) {
    unsigned u = __float_as_uint(f);
    u += 0x7FFFu + ((u >> 16) & 1u);
    return (unsigned short)(u >> 16);
}
__device__ inline float bf2f(unsigned short s) {
    return __uint_as_float((unsigned)s << 16);
}
__device__ inline float4 bf4(ushort4 u) {
    return make_float4(bf2f(u.x), bf2f(u.y), bf2f(u.z), bf2f(u.w));
}

// ============ phase B: scatter edges into per-(bucket,segment) arenas ============
__global__ void k_bucket_scatter(const int* __restrict__ src, const int* __restrict__ dst,
                                 int* __restrict__ cur, int* __restrict__ arena, int E) {
    int e = blockIdx.x * blockDim.x + threadIdx.x;
    if (e >= E) return;
    int d = dst[e];
    int b = d >> BSH;
    int slot = b * NSEG + (blockIdx.x & (NSEG - 1));
    int p = atomicAdd(&cur[slot * CSTR], 1);
    if (p < SEGCAP) arena[slot * SEGCAP + p] = (src[e] << BSH) | (d & 63);
}

// ============ scan bucket totals -> bucket base offsets (single block; nbk <= 1024) ============
__global__ __launch_bounds__(1024) void k_bucket_scan(const int* __restrict__ cur,
                                                      int* __restrict__ bbase,
                                                      int* __restrict__ rowptr,
                                                      int nbk, int n, int E) {
    __shared__ int t[1024];
    int b = threadIdx.x;
    int v = 0;
    if (b < nbk) {
        #pragma unroll
        for (int s = 0; s < NSEG; ++s) v += cur[(b * NSEG + s) * CSTR];
    }
    t[b] = v;
    __syncthreads();
    for (int off = 1; off < 1024; off <<= 1) {
        int add = (b >= off) ? t[b - off] : 0;
        __syncthreads();
        t[b] += add;
        __syncthreads();
    }
    if (b < nbk) bbase[b] = t[b] - v;  // exclusive
    if (b == 0) rowptr[n] = E;
}

// ============ phase C: per-bucket counting sort -> rowptr, dinv, compact src_sorted ============
__global__ __launch_bounds__(256) void k_bucket_sort(const int* __restrict__ arena,
                                                     const int* __restrict__ cur,
                                                     const int* __restrict__ bbase,
                                                     int* __restrict__ rowptr,
                                                     float* __restrict__ dinv,
                                                     int* __restrict__ src_sorted, int n) {
    const int b = blockIdx.x;
    const int base = bbase[b];
    __shared__ int cnt[64], off[64];
    if (threadIdx.x < 64) cnt[threadIdx.x] = 0;
    __syncthreads();
    for (int s = 0; s < NSEG; ++s) {
        const int len = cur[(b * NSEG + s) * CSTR];
        const int* seg = arena + (size_t)(b * NSEG + s) * SEGCAP;
        for (int idx = threadIdx.x; idx < len; idx += 256)
            atomicAdd(&cnt[seg[idx] & 63], 1);
    }
    __syncthreads();
    if (threadIdx.x == 0) {
        int run = 0;
        for (int j = 0; j < 64; ++j) { off[j] = run; run += cnt[j]; }
    }
    __syncthreads();
    if (threadIdx.x < 64) {
        int node = (b << BSH) + threadIdx.x;
        if (node < n) {
            rowptr[node] = base + off[threadIdx.x];
            dinv[node] = rsqrtf((float)cnt[threadIdx.x] + 1.0f);  // +1 self-loop
        }
    }
    __syncthreads();
    for (int s = 0; s < NSEG; ++s) {
        const int len = cur[(b * NSEG + s) * CSTR];
        const int* seg = arena + (size_t)(b * NSEG + s) * SEGCAP;
        for (int idx = threadIdx.x; idx < len; idx += 256) {
            int v = seg[idx];
            int lpos = atomicAdd(&off[v & 63], 1);
            src_sorted[base + lpos] = v >> BSH;
        }
    }
}

// ====== MFMA bf16 GEMM: 128-row block, 4 waves in 2x2 (64 rows x ~half cols each) ======
// A fp32 [n][KIN] -> bf16 LDS (K zero-padded to KP). W fp32 [KIN][KOUT] -> bf16 LDS transposed Wt[c][k].
// mfma_f32_16x16x32_bf16: A-frag A[m=lane&15][k=quad*8+j]; B-frag B[k=quad*8+j][n=lane&15];
// C/D: col=lane&15, row=quad*4+reg  (learn_hip m89/m91 verified).
template <int KIN, int KOUT, bool RELU_IN, bool BIAS, bool OUT_BF16>
__global__ __launch_bounds__(256) void k_gemm_mfma(const float* __restrict__ A,
                                                   const float* __restrict__ W,
                                                   const float* __restrict__ bias,
                                                   void* __restrict__ C, int n) {
    constexpr int KP   = ((KIN + 31) / 32) * 32;  // K padded to mult of 32
    constexpr int NT   = (KOUT + 15) / 16;        // 16-col tiles
    constexpr int NTC  = NT * 16;
    constexpr int APAD = KP + 8;                  // LDS stride (shorts), mult of 8 -> 16B-aligned b128
    constexpr int NKC  = KP / 32;                 // K chunks per mfma loop
    constexpr int TQ   = (NT + 1) / 2;            // col tiles per wave (max)
    constexpr int KQ4  = KIN / 4;

    __shared__ unsigned short Abf[128 * APAD];
    __shared__ unsigned short Wt[NTC * APAD];

    const int row0 = blockIdx.x * 128;
    const int tid = threadIdx.x;

    // ---- stage A rows as bf16 (coalesced float4 reads, b64 LDS writes) ----
    for (int idx = tid; idx < 128 * KQ4; idx += 256) {
        int r = idx / KQ4;
        int kq = idx - r * KQ4;
        float4 v = make_float4(0.f, 0.f, 0.f, 0.f);
        if (row0 + r < n) {
            v = ((const float4*)(A + (size_t)(row0 + r) * KIN))[kq];
            if (RELU_IN) {
                v.x = fmaxf(v.x, 0.f); v.y = fmaxf(v.y, 0.f);
                v.z = fmaxf(v.z, 0.f); v.w = fmaxf(v.w, 0.f);
            }
        }
        ushort4 o;
        o.x = f2bf(v.x); o.y = f2bf(v.y); o.z = f2bf(v.z); o.w = f2bf(v.w);
        *(ushort4*)&Abf[r * APAD + kq * 4] = o;
    }
    if (KP > KIN) {
        constexpr int PADW = (KP > KIN) ? (KP - KIN) : 1;
        for (int idx = tid; idx < 128 * PADW; idx += 256) {
            int r = idx / PADW;
            Abf[r * APAD + KIN + (idx - r * PADW)] = 0;
        }
    }
    // ---- stage W transposed (coalesced global reads along c; scalar b16 LDS writes) ----
    for (int idx = tid; idx < KIN * NTC; idx += 256) {
        int k = idx / NTC;
        int c = idx - k * NTC;
        float v = (c < KOUT) ? W[(size_t)k * KOUT + c] : 0.f;
        Wt[c * APAD + k] = f2bf(v);
    }
    if (KP > KIN) {
        constexpr int PADW = (KP > KIN) ? (KP - KIN) : 1;
        for (int idx = tid; idx < NTC * PADW; idx += 256) {
            int c = idx / PADW;
            Wt[c * APAD + KIN + (idx - c * PADW)] = 0;
        }
    }
    __syncthreads();

    const int lane = tid & 63;
    const int w    = tid >> 6;
    const int m0   = (w >> 1) * 64;              // wave row base (0 or 64)
    const int t0   = (w & 1) * TQ;               // wave col-tile base
    const int tcnt = (NT - t0 < TQ) ? (NT - t0) : TQ;
    const int lm   = lane & 15;
    const int quad = lane >> 4;

    f32x4 acc[4][TQ];
    #pragma unroll
    for (int i = 0; i < 4; ++i)
        #pragma unroll
        for (int t = 0; t < TQ; ++t)
            acc[i][t] = (f32x4)(0.f);

    for (int kt = 0; kt < NKC; ++kt) {
        short8 a[4], b[TQ];
        #pragma unroll
        for (int i = 0; i < 4; ++i)
            a[i] = *(const short8*)&Abf[(m0 + i * 16 + lm) * APAD + kt * 32 + quad * 8];
        #pragma unroll
        for (int t = 0; t < TQ; ++t)
            if (t < tcnt)
                b[t] = *(const short8*)&Wt[((t0 + t) * 16 + lm) * APAD + kt * 32 + quad * 8];
        #pragma unroll
        for (int i = 0; i < 4; ++i)
            #pragma unroll
            for (int t = 0; t < TQ; ++t)
                if (t < tcnt)
                    acc[i][t] = __builtin_amdgcn_mfma_f32_16x16x32_bf16(a[i], b[t], acc[i][t], 0, 0, 0);
    }

    // ---- epilogue: C/D layout col=lane&15, row=quad*4+reg ----
    #pragma unroll
    for (int t = 0; t < TQ; ++t) {
        if (t >= tcnt) continue;
        int col = (t0 + t) * 16 + lm;
        if (col >= KOUT) continue;
        float bv = BIAS ? bias[col] : 0.f;
        #pragma unroll
        for (int i = 0; i < 4; ++i) {
            #pragma unroll
            for (int rg = 0; rg < 4; ++rg) {
                int row = row0 + m0 + i * 16 + quad * 4 + rg;
                if (row < n) {
                    float v = acc[i][t][rg] + bv;
                    if (OUT_BF16)
                        ((unsigned short*)C)[(size_t)row * KOUT + col] = f2bf(v);
                    else
                        ((float*)C)[(size_t)row * KOUT + col] = v;
                }
            }
        }
    }
}

// ===== row-major CSR aggregation over bf16 h: out_i = b + d_i*(d_i*h_i + sum dinv[s]*h[s]) =====
template <int F>
__global__ __launch_bounds__(256) void k_agg_bf(const unsigned short* __restrict__ h,
                                                const int* __restrict__ rowptr,
                                                const int* __restrict__ src_sorted,
                                                const float* __restrict__ dinv,
                                                const float* __restrict__ bias,
                                                float* __restrict__ out, int n) {
    const int G = F / 4;
    int gid = blockIdx.x * blockDim.x + threadIdx.x;
    if (gid >= n * G) return;
    int i = gid / G;
    int cq = gid % G;
    const ushort4* h4 = (const ushort4*)h;

    float4 acc = make_float4(0.f, 0.f, 0.f, 0.f);
    int e = rowptr[i];
    const int end = rowptr[i + 1];
    for (; e + 3 < end; e += 4) {
        int s0 = src_sorted[e];
        int s1 = src_sorted[e + 1];
        int s2 = src_sorted[e + 2];
        int s3 = src_sorted[e + 3];
        ushort4 u0 = h4[(size_t)s0 * G + cq];
        ushort4 u1 = h4[(size_t)s1 * G + cq];
        ushort4 u2 = h4[(size_t)s2 * G + cq];
        ushort4 u3 = h4[(size_t)s3 * G + cq];
        float n0 = dinv[s0], n1 = dinv[s1], n2 = dinv[s2], n3 = dinv[s3];
        float4 v0 = bf4(u0), v1 = bf4(u1), v2 = bf4(u2), v3 = bf4(u3);
        acc.x = fmaf(v0.x, n0, acc.x); acc.y = fmaf(v0.y, n0, acc.y);
        acc.z = fmaf(v0.z, n0, acc.z); acc.w = fmaf(v0.w, n0, acc.w);
        acc.x = fmaf(v1.x, n1, acc.x); acc.y = fmaf(v1.y, n1, acc.y);
        acc.z = fmaf(v1.z, n1, acc.z); acc.w = fmaf(v1.w, n1, acc.w);
        acc.x = fmaf(v2.x, n2, acc.x); acc.y = fmaf(v2.y, n2, acc.y);
        acc.z = fmaf(v2.z, n2, acc.z); acc.w = fmaf(v2.w, n2, acc.w);
        acc.x = fmaf(v3.x, n3, acc.x); acc.y = fmaf(v3.y, n3, acc.y);
        acc.z = fmaf(v3.z, n3, acc.z); acc.w = fmaf(v3.w, n3, acc.w);
    }
    for (; e < end; ++e) {
        int s0 = src_sorted[e];
        float n0 = dinv[s0];
        float4 v0 = bf4(h4[(size_t)s0 * G + cq]);
        acc.x = fmaf(v0.x, n0, acc.x); acc.y = fmaf(v0.y, n0, acc.y);
        acc.z = fmaf(v0.z, n0, acc.z); acc.w = fmaf(v0.w, n0, acc.w);
    }

    float d = dinv[i];
    float4 hv = bf4(h4[(size_t)i * G + cq]);
    float4 bv = *(const float4*)&bias[cq * 4];
    float4 o;
    o.x = fmaf(d, fmaf(d, hv.x, acc.x), bv.x);
    o.y = fmaf(d, fmaf(d, hv.y, acc.y), bv.y);
    o.z = fmaf(d, fmaf(d, hv.z, acc.z), bv.z);
    o.w = fmaf(d, fmaf(d, hv.w, acc.w), bv.w);
    ((float4*)out)[(size_t)i * G + cq] = o;
}

extern "C" void kernel_launch(void* const* d_in, const int* in_sizes, int n_in,
                              void* d_out, int out_size, void* d_ws, size_t ws_size,
                              hipStream_t stream) {
    const float* x  = (const float*)d_in[0];
    const int*   ei = (const int*)d_in[1];
    const float* W1 = (const float*)d_in[2];
    const float* b1 = (const float*)d_in[3];
    const float* W2 = (const float*)d_in[4];
    const float* b2 = (const float*)d_in[5];
    const float* Wc = (const float*)d_in[6];
    const float* bc = (const float*)d_in[7];
    float* out = (float*)d_out;

    const int N = in_sizes[0] / FIN;
    const int E = in_sizes[1] / 2;
    const int* src = ei;
    const int* dst = ei + E;
    const int NBK = (N + 63) >> BSH;  // 782 for N=50k; k_bucket_scan requires <= 1024

    auto align = [](size_t v) { return (v + 255) & ~(size_t)255; };
    char* ws = (char*)d_ws;
    int*   cur        = (int*)ws;   ws += align((size_t)NBK * NSEG * CSTR * 4);
    int*   bbase      = (int*)ws;   ws += align((size_t)(NBK + 1) * 4);
    int*   arena      = (int*)ws;   ws += align((size_t)NBK * NSEG * SEGCAP * 4);
    int*   rowptr     = (int*)ws;   ws += align((size_t)(N + 1) * 4);
    int*   src_sorted = (int*)ws;   ws += align((size_t)E * 4);
    float* dinv       = (float*)ws; ws += align((size_t)N * 4);
    unsigned short* hbf = (unsigned short*)ws; ws += align((size_t)N * FHID * 2);  // bf16 h1/h2
    float* abuf       = (float*)ws; ws += align((size_t)N * FHID * 4);             // fp32 a1/a2

    const int B = 256;
    const int nmb = (N + 127) / 128;  // MFMA 128-row tiles

    // --- bucketed counting sort (CSR shared by both conv layers) ---
    hipMemsetAsync(cur, 0, (size_t)NBK * NSEG * CSTR * 4, stream);
    k_bucket_scatter<<<(E + B - 1) / B, B, 0, stream>>>(src, dst, cur, arena, E);
    k_bucket_scan<<<1, 1024, 0, stream>>>(cur, bbase, rowptr, NBK, N, E);
    k_bucket_sort<<<NBK, B, 0, stream>>>(arena, cur, bbase, rowptr, dinv, src_sorted, N);

    // --- layer 1: h1(bf16) = x @ W1 ; a1 = agg(h1) + b1 ---
    k_gemm_mfma<FIN, FHID, false, false, true><<<nmb, B, 0, stream>>>(x, W1, nullptr, hbf, N);
    k_agg_bf<FHID><<<((size_t)N * (FHID / 4) + B - 1) / B, B, 0, stream>>>(
        hbf, rowptr, src_sorted, dinv, b1, abuf, N);

    // --- layer 2: h2(bf16) = relu(a1) @ W2 ; a2 = agg(h2) + b2 ---
    k_gemm_mfma<FHID, FEMB, true, false, true><<<nmb, B, 0, stream>>>(abuf, W2, nullptr, hbf, N);
    k_agg_bf<FEMB><<<((size_t)N * (FEMB / 4) + B - 1) / B, B, 0, stream>>>(
        hbf, rowptr, src_sorted, dinv, b2, abuf, N);

    // --- classifier: out = relu(a2) @ Wc + bc ---
    k_gemm_mfma<FEMB, NCLS, true, true, false><<<nmb, B, 0, stream>>>(abuf, Wc, bc, out, N);
}